// Round 12
// baseline (422.007 us; speedup 1.0000x reference)
//
#include <hip/hip_runtime.h>
#include <hip/hip_bf16.h>

// TransformerEncLayer on MI355X (gfx950). B=2, M=2048, d=1024, H=16, DK=64, FF=4096.
// Tokens = 4096. LN grids = 4096.
// R12 = R11 with the compile fix: __exp2f (glibc macro collision) ->
// __builtin_amdgcn_exp2f (raw v_exp_f32 = 2^x on gfx950).
//  (1) ff2 split-K x4 into ONE f32 accumulator via atomicAdd (grid
//      (16,32,4) = 8 blocks/CU; R10 showed ff2 fetch-bound: 135 MB @ 2.36 TB/s,
//      occupancy 36% -> concurrency-limited). Acc buffer (16 MB f32) zeroed by
//      hipMemsetAsync (graph-legal) in dead xc/WqkvT/W1T regions; ln2 reads f32.
//  (2) attn: log2(e)/1024 folded into Q pre-scale -> exp2, kills the
//      per-score v_mul before v_exp_f32.
// Attention split-KV x2 (R10), MFMA denominator (R9), fused QKV (R7).

typedef __bf16 bf16;
typedef __attribute__((ext_vector_type(8))) __bf16 bf16x8;
typedef __attribute__((ext_vector_type(4))) __bf16 bf16x4;
typedef __attribute__((ext_vector_type(4))) float f32x4;

#define MFMA16(a, b, c) __builtin_amdgcn_mfma_f32_16x16x32_bf16(a, b, c, 0, 0, 0)

__device__ __forceinline__ void ld_g2l16(void* lds, const void* g) {
  __builtin_amdgcn_global_load_lds((const __attribute__((address_space(1))) void*)g,
                                   (__attribute__((address_space(3))) void*)lds,
                                   16, 0, 0);
}

// ---------------------------------------------------------------------------
// dtype detector (flag=1 -> fp32 inputs)
// ---------------------------------------------------------------------------
__global__ __launch_bounds__(256) void detect_dtype(const void* __restrict__ x,
                                                    int* __restrict__ flag) {
  const unsigned short* u = (const unsigned short*)x;
  int cnt = 0;
  for (int i = threadIdx.x; i < 4096; i += 256) {
    const int e = (u[i] >> 7) & 0xFF;
    if (e >= 140) ++cnt;
  }
  __shared__ int sh[256];
  sh[threadIdx.x] = cnt;
  __syncthreads();
  for (int s = 128; s > 0; s >>= 1) {
    if (threadIdx.x < s) sh[threadIdx.x] += sh[threadIdx.x + s];
    __syncthreads();
  }
  if (threadIdx.x == 0) *flag = (sh[0] > 100) ? 1 : 0;
}

__device__ __forceinline__ bf16 load_any(const void* p, size_t i, int fl) {
  return fl ? (bf16)((const float*)p)[i] : ((const bf16*)p)[i];
}

__global__ __launch_bounds__(256) void convert_x(const void* __restrict__ in,
                                                 bf16* __restrict__ o,
                                                 const int* __restrict__ flag) {
  const int fl = *flag;
  const size_t i0 = (size_t)(blockIdx.x * 256 + threadIdx.x) * 4;
#pragma unroll
  for (int i = 0; i < 4; ++i) o[i0 + i] = load_any(in, i0 + i, fl);
}

// small vectors -> packed bf16: bqkv[3072] | b1[4096] | b2 | g1 | be1 | g2 | be2
__global__ __launch_bounds__(256) void convert_small(
    const void* p0, const void* p1, const void* p2, const void* p3,
    const void* p4, const void* p5, const void* p6, const void* p7,
    const void* p8, bf16* __restrict__ dst, const int* __restrict__ flag) {
  const int fl = *flag;
  const int t = blockIdx.x * 256 + threadIdx.x;  // 0..4095
  const void* ps[9] = {p0, p1, p2, p3, p4, p5, p6, p7, p8};
  const int sz[9]  = {1024, 1024, 1024, 4096, 1024, 1024, 1024, 1024, 1024};
  const int off[9] = {0, 1024, 2048, 3072, 7168, 8192, 9216, 10240, 11264};
#pragma unroll
  for (int a = 0; a < 9; ++a)
    if (t < sz[a]) dst[off[a] + t] = load_any(ps[a], t, fl);
}

// ---------------------------------------------------------------------------
// flag-aware transpose: in[R][C] (bf16 or fp32) -> out[C][R] bf16.
// ---------------------------------------------------------------------------
__global__ __launch_bounds__(256) void transpose_w(const void* __restrict__ in,
                                                   bf16* __restrict__ out,
                                                   int R, int C,
                                                   const int* __restrict__ flag) {
  const int fl = *flag;
  __shared__ bf16 t[32][33];
  const int r0 = blockIdx.y * 32, c0 = blockIdx.x * 32;
  const int tx = threadIdx.x, ty = threadIdx.y;
#pragma unroll
  for (int i = ty; i < 32; i += 8)
    t[i][tx] = load_any(in, (size_t)(r0 + i) * C + c0 + tx, fl);
  __syncthreads();
#pragma unroll
  for (int i = ty; i < 32; i += 8)
    out[(size_t)(c0 + i) * R + r0 + tx] = t[tx][i];
}

// three 1024x1024 transposes in one launch (z selects Wq/Wk/Wv) -> WqkvT
__global__ __launch_bounds__(256) void transpose_w3(const void* __restrict__ q,
                                                    const void* __restrict__ k,
                                                    const void* __restrict__ v,
                                                    bf16* __restrict__ out,
                                                    const int* __restrict__ flag) {
  const int fl = *flag;
  const int z = blockIdx.z;
  const void* in = (z == 0) ? q : (z == 1) ? k : v;
  bf16* o = out + (size_t)z * 1024 * 1024;
  __shared__ bf16 t[32][33];
  const int r0 = blockIdx.y * 32, c0 = blockIdx.x * 32;
  const int tx = threadIdx.x, ty = threadIdx.y;
#pragma unroll
  for (int i = ty; i < 32; i += 8)
    t[i][tx] = load_any(in, (size_t)(r0 + i) * 1024 + c0 + tx, fl);
  __syncthreads();
#pragma unroll
  for (int i = ty; i < 32; i += 8)
    o[(size_t)(c0 + i) * 1024 + r0 + tx] = t[tx][i];
}

// ---------------------------------------------------------------------------
// V transpose per head from fused qkvb: qkvb[4096][3072] (v at col 2048+)
// -> vT[b*16+h][64][2048]
// ---------------------------------------------------------------------------
__global__ __launch_bounds__(256) void transpose_v(const bf16* __restrict__ qkvb,
                                                   bf16* __restrict__ vT) {
  __shared__ bf16 t[32][33];
  const int bh = blockIdx.z;
  const int b = bh >> 4, h = bh & 15;
  const int m0 = blockIdx.x * 32, d0 = blockIdx.y * 32;
  const int tx = threadIdx.x, ty = threadIdx.y;
#pragma unroll
  for (int i = ty; i < 32; i += 8)
    t[i][tx] = qkvb[(size_t)(b * 2048 + m0 + i) * 3072 + 2048 + h * 64 + d0 + tx];
  __syncthreads();
#pragma unroll
  for (int i = ty; i < 32; i += 8)
    vT[((size_t)bh * 64 + d0 + i) * 2048 + m0 + tx] = t[tx][i];
}

// ---------------------------------------------------------------------------
// bt-GEMM 128x128: C[M][N] = A[M][K] @ BT[N][K]^T + bias, optional ReLU.
// ---------------------------------------------------------------------------
__global__ __launch_bounds__(256) void gemm_bt(const bf16* __restrict__ A,
                                               const bf16* __restrict__ BT,
                                               const bf16* __restrict__ bias,
                                               bf16* __restrict__ C,
                                               int M, int N, int K, int relu) {
  __shared__ bf16 sA[128 * 32];
  __shared__ bf16 sB[128 * 32];
  const int tid = threadIdx.x;
  const int wave = tid >> 6, lane = tid & 63;
  const int wm = wave >> 1, wn = wave & 1;
  const int bm = blockIdx.y * 128, bn = blockIdx.x * 128;
  const int m16 = lane & 15, kg = lane >> 4;
  const int srow = lane >> 2;
  const int scol = (lane & 3) * 8;

  f32x4 acc[4][4];
#pragma unroll
  for (int i = 0; i < 4; ++i)
#pragma unroll
    for (int j = 0; j < 4; ++j) acc[i][j] = (f32x4){0.f, 0.f, 0.f, 0.f};

  for (int k0 = 0; k0 < K; k0 += 32) {
#pragma unroll
    for (int i = 0; i < 2; ++i) {
      const int c = wave * 2 + i;
      const int row = c * 16 + srow;
      ld_g2l16(&sA[c * 512], A + (size_t)(bm + row) * K + k0 + scol);
      ld_g2l16(&sB[c * 512], BT + (size_t)(bn + row) * K + k0 + scol);
    }
    __syncthreads();

    bf16x8 af[4], bfr[4];
#pragma unroll
    for (int t = 0; t < 4; ++t) {
      af[t]  = *(const bf16x8*)&sA[(wm * 64 + t * 16 + m16) * 32 + kg * 8];
      bfr[t] = *(const bf16x8*)&sB[(wn * 64 + t * 16 + m16) * 32 + kg * 8];
    }
#pragma unroll
    for (int mt = 0; mt < 4; ++mt)
#pragma unroll
      for (int nt = 0; nt < 4; ++nt)
        acc[mt][nt] = MFMA16(af[mt], bfr[nt], acc[mt][nt]);
    __syncthreads();
  }

  const int r0 = bm + wm * 64, c0 = bn + wn * 64;
#pragma unroll
  for (int nt = 0; nt < 4; ++nt) {
    const int col = c0 + nt * 16 + m16;
    const float bv = (float)bias[col];
#pragma unroll
    for (int mt = 0; mt < 4; ++mt) {
#pragma unroll
      for (int r = 0; r < 4; ++r) {
        const int row = r0 + mt * 16 + kg * 4 + r;
        float v = acc[mt][nt][r] + bv;
        if (relu) v = fmaxf(v, 0.f);
        C[(size_t)row * N + col] = (bf16)v;
      }
    }
  }
}

// ---------------------------------------------------------------------------
// Split-K x4 bt-GEMM 128x64 tile -> f32 accumulator via atomicAdd.
// blockIdx.z in [0,4): K-quarter [z*Kp, z*Kp+Kp). Cacc must be pre-zeroed.
// ---------------------------------------------------------------------------
__global__ __launch_bounds__(256) void gemm_bt64_sk4(const bf16* __restrict__ A,
                                                     const bf16* __restrict__ BT,
                                                     float* __restrict__ Cacc,
                                                     int M, int N, int Kf, int Kp) {
  __shared__ bf16 sA[128 * 32];
  __shared__ bf16 sB[64 * 32];
  const int tid = threadIdx.x;
  const int wave = tid >> 6, lane = tid & 63;
  const int bm = blockIdx.y * 128, bn = blockIdx.x * 64;
  const int kbase = blockIdx.z * Kp;
  const int m16 = lane & 15, kg = lane >> 4;
  const int srow = lane >> 2;
  const int scol = (lane & 3) * 8;

  f32x4 acc[2][4];
#pragma unroll
  for (int i = 0; i < 2; ++i)
#pragma unroll
    for (int j = 0; j < 4; ++j) acc[i][j] = (f32x4){0.f, 0.f, 0.f, 0.f};

  for (int k0 = 0; k0 < Kp; k0 += 32) {
#pragma unroll
    for (int i = 0; i < 2; ++i) {
      const int c = wave * 2 + i;
      ld_g2l16(&sA[c * 512],
               A + (size_t)(bm + c * 16 + srow) * Kf + kbase + k0 + scol);
    }
    ld_g2l16(&sB[wave * 512],
             BT + (size_t)(bn + wave * 16 + srow) * Kf + kbase + k0 + scol);
    __syncthreads();

    bf16x8 af[2], bfr[4];
#pragma unroll
    for (int t = 0; t < 2; ++t)
      af[t] = *(const bf16x8*)&sA[(wave * 32 + t * 16 + m16) * 32 + kg * 8];
#pragma unroll
    for (int t = 0; t < 4; ++t)
      bfr[t] = *(const bf16x8*)&sB[(t * 16 + m16) * 32 + kg * 8];
#pragma unroll
    for (int mt = 0; mt < 2; ++mt)
#pragma unroll
      for (int nt = 0; nt < 4; ++nt)
        acc[mt][nt] = MFMA16(af[mt], bfr[nt], acc[mt][nt]);
    __syncthreads();
  }

  const int r0 = bm + wave * 32;
#pragma unroll
  for (int nt = 0; nt < 4; ++nt) {
    const int col = bn + nt * 16 + m16;
#pragma unroll
    for (int mt = 0; mt < 2; ++mt) {
#pragma unroll
      for (int r = 0; r < 4; ++r) {
        const int row = r0 + mt * 16 + kg * 4 + r;
        atomicAdd(&Cacc[(size_t)row * N + col], acc[mt][nt][r]);
      }
    }
  }
}

// ---------------------------------------------------------------------------
// Staged flash attention, split-KV x2. grid (16 qtiles, 16 heads, 4), z=b*2+kh.
// Q pre-scaled by log2(e)/1024 -> P = 2^S' via __builtin_amdgcn_exp2f
// (v_exp_f32). Unnormalized bf16 o partials + f32 den partials; combined in ln1.
// ---------------------------------------------------------------------------
__global__ __launch_bounds__(256) void attn_kernel(const bf16* __restrict__ qkvb,
                                                   const bf16* __restrict__ vT,
                                                   bf16* __restrict__ op0,
                                                   bf16* __restrict__ op1,
                                                   float* __restrict__ den0,
                                                   float* __restrict__ den1) {
  __shared__ bf16 sK[2][64 * 32];
  __shared__ bf16 sV[2][64 * 32];
  __shared__ bf16 pl[4][2][16 * 72];
  const int qt = blockIdx.x, h = blockIdx.y;
  const int b = blockIdx.z >> 1, kh = blockIdx.z & 1;
  const int tid = threadIdx.x, wv = tid >> 6, lane = tid & 63;
  const int m16 = lane & 15, kg = lane >> 4;
  const int srow = lane >> 2;
  const int scol = (lane & 3) * 8;

  // Q fragments pre-scaled by log2(e)/1024 -> S' = S*log2(e)/1024, P = 2^S'
  const float qs = 1.4426950408889634f / 1024.0f;
  bf16x8 fq0[2], fq1[2];
#pragma unroll
  for (int f = 0; f < 2; ++f) {
    const int q0 = qt * 128 + f * 64 + wv * 16;
    const bf16* qp = qkvb + (size_t)(b * 2048 + q0 + m16) * 3072 + h * 64;
    bf16x8 a = *(const bf16x8*)(qp + kg * 8);
    bf16x8 c = *(const bf16x8*)(qp + 32 + kg * 8);
#pragma unroll
    for (int i = 0; i < 8; ++i) {
      a[i] = (bf16)((float)a[i] * qs);
      c[i] = (bf16)((float)c[i] * qs);
    }
    fq0[f] = a;
    fq1[f] = c;
  }

  bf16x8 ones;
#pragma unroll
  for (int i = 0; i < 8; ++i) ones[i] = (bf16)1.0f;

  f32x4 o[2][4], oden[2];
#pragma unroll
  for (int f = 0; f < 2; ++f) {
#pragma unroll
    for (int c = 0; c < 4; ++c) o[f][c] = (f32x4){0.f, 0.f, 0.f, 0.f};
    oden[f] = (f32x4){0.f, 0.f, 0.f, 0.f};
  }

  const bf16* kbase = qkvb + (size_t)(b * 2048) * 3072 + 1024 + h * 64;
  const bf16* vbase = vT + (size_t)(b * 16 + h) * 64 * 2048;
  bf16* plw0 = &pl[wv][0][0];
  bf16* plw1 = &pl[wv][1][0];

  const int tstart = kh * 1024;
  for (int t0 = tstart; t0 < tstart + 1024; t0 += 64) {
    {
      const int row = wv * 16 + srow;
      ld_g2l16(&sK[0][wv * 512], kbase + (size_t)(t0 + row) * 3072 + scol);
      ld_g2l16(&sK[1][wv * 512], kbase + (size_t)(t0 + row) * 3072 + 32 + scol);
      ld_g2l16(&sV[0][wv * 512], vbase + (size_t)row * 2048 + t0 + scol);
      ld_g2l16(&sV[1][wv * 512], vbase + (size_t)row * 2048 + t0 + 32 + scol);
    }
    __syncthreads();

#pragma unroll
    for (int g = 0; g < 4; ++g) {
      const bf16x8 af0 = *(const bf16x8*)&sK[0][(g * 16 + m16) * 32 + kg * 8];
      const bf16x8 af1 = *(const bf16x8*)&sK[1][(g * 16 + m16) * 32 + kg * 8];
#pragma unroll
      for (int f = 0; f < 2; ++f) {
        f32x4 z = (f32x4){0.f, 0.f, 0.f, 0.f};
        z = MFMA16(af0, fq0[f], z);   // S'^T[t][q], exp2 domain
        z = MFMA16(af1, fq1[f], z);
        bf16x4 pv4;
#pragma unroll
        for (int r = 0; r < 4; ++r)
          pv4[r] = (bf16)__builtin_amdgcn_exp2f(z[r]);
        *(bf16x4*)((f ? plw1 : plw0) + m16 * 72 + g * 16 + kg * 4) = pv4;
      }
    }
    __asm__ __volatile__("s_waitcnt lgkmcnt(0)" ::: "memory");

#pragma unroll
    for (int tt = 0; tt < 2; ++tt) {
      const bf16x8 pa0 = *(const bf16x8*)(plw0 + m16 * 72 + tt * 32 + kg * 8);
      const bf16x8 pa1 = *(const bf16x8*)(plw1 + m16 * 72 + tt * 32 + kg * 8);
      oden[0] = MFMA16(pa0, ones, oden[0]);   // den[q=kg*4+r] in every col
      oden[1] = MFMA16(pa1, ones, oden[1]);
#pragma unroll
      for (int c = 0; c < 4; ++c) {
        const bf16x8 fv = *(const bf16x8*)&sV[tt][(c * 16 + m16) * 32 + kg * 8];
        o[0][c] = MFMA16(pa0, fv, o[0][c]);
        o[1][c] = MFMA16(pa1, fv, o[1][c]);
      }
    }
    __syncthreads();
  }

  bf16* op = kh ? op1 : op0;
  float* dptr = kh ? den1 : den0;
#pragma unroll
  for (int f = 0; f < 2; ++f)
#pragma unroll
    for (int r = 0; r < 4; ++r) {
      const int row = qt * 128 + f * 64 + wv * 16 + kg * 4 + r;  // q in [0,2048)
      if (m16 == 0) dptr[((b * 16 + h) << 11) + row] = oden[f][r];
      bf16* opp = op + (size_t)(b * 2048 + row) * 1024 + h * 64;
#pragma unroll
      for (int c = 0; c < 4; ++c) opp[c * 16 + m16] = (bf16)o[f][c][r];
    }
}

// ---------------------------------------------------------------------------
// LN1 + attention combine: attn = (op0+op1) / (den0+den1), then
// h1b = bf16( LN(x + attn)*g1 + be1 ). grid = 4096 rows.
// op1 aliases h1b: reads precede the barrier, writes follow; same-thread cover.
// ---------------------------------------------------------------------------
__global__ __launch_bounds__(256) void ln1_kernel(const bf16* __restrict__ x,
                                                  const bf16* __restrict__ op0,
                                                  const bf16* __restrict__ op1,
                                                  const float* __restrict__ den0,
                                                  const float* __restrict__ den1,
                                                  const bf16* __restrict__ g,
                                                  const bf16* __restrict__ be,
                                                  bf16* __restrict__ h1b) {
  const int row = blockIdx.x;           // b*2048 + q
  const int b = row >> 11, q = row & 2047;
  const size_t base = (size_t)row * 1024;
  const int t = threadIdx.x;
  const int h = t >> 4;                 // head of this thread's 4 columns
  const float rden = 1.0f / (den0[((b * 16 + h) << 11) + q] +
                             den1[((b * 16 + h) << 11) + q]);
  float v[4], s = 0.f, ss = 0.f;
#pragma unroll
  for (int i = 0; i < 4; ++i) {
    const int c = t * 4 + i;
    const float at = ((float)op0[base + c] + (float)op1[base + c]) * rden;
    const float xv = (float)x[base + c] + at;
    v[i] = xv; s += xv; ss += xv * xv;
  }
#pragma unroll
  for (int m = 1; m < 64; m <<= 1) { s += __shfl_xor(s, m); ss += __shfl_xor(ss, m); }
  __shared__ float rs[4], rss[4];
  const int wave = t >> 6, lane = t & 63;
  if (lane == 0) { rs[wave] = s; rss[wave] = ss; }
  __syncthreads();
  s = rs[0] + rs[1] + rs[2] + rs[3];
  ss = rss[0] + rss[1] + rss[2] + rss[3];
  const float mu = s * (1.f / 1024.f);
  const float var = fmaxf(ss * (1.f / 1024.f) - mu * mu, 0.f);
  const float rstd = rsqrtf(var + 1e-5f);
#pragma unroll
  for (int i = 0; i < 4; ++i) {
    const int c = t * 4 + i;
    h1b[base + c] = (bf16)((v[i] - mu) * rstd * (float)g[c] + (float)be[c]);
  }
}

// LN2: out = LN(h1b + facc + b2)*g2 + be2 ; out dtype per flag. grid = 4096.
__global__ __launch_bounds__(256) void ln2_kernel(const bf16* __restrict__ h1b,
                                                  const float* __restrict__ facc,
                                                  const bf16* __restrict__ b2,
                                                  const bf16* __restrict__ g,
                                                  const bf16* __restrict__ be,
                                                  void* __restrict__ out,
                                                  const int* __restrict__ flag) {
  const int fl = *flag;
  const int row = blockIdx.x;
  const size_t base = (size_t)row * 1024;
  const int t = threadIdx.x;
  float v[4], s = 0.f, ss = 0.f;
#pragma unroll
  for (int i = 0; i < 4; ++i) {
    const int c = t * 4 + i;
    const float xv = (float)h1b[base + c] + facc[base + c] + (float)b2[c];
    v[i] = xv; s += xv; ss += xv * xv;
  }
#pragma unroll
  for (int m = 1; m < 64; m <<= 1) { s += __shfl_xor(s, m); ss += __shfl_xor(ss, m); }
  __shared__ float rs[4], rss[4];
  const int wave = t >> 6, lane = t & 63;
  if (lane == 0) { rs[wave] = s; rss[wave] = ss; }
  __syncthreads();
  s = rs[0] + rs[1] + rs[2] + rs[3];
  ss = rss[0] + rss[1] + rss[2] + rss[3];
  const float mu = s * (1.f / 1024.f);
  const float var = fmaxf(ss * (1.f / 1024.f) - mu * mu, 0.f);
  const float rstd = rsqrtf(var + 1e-5f);
#pragma unroll
  for (int i = 0; i < 4; ++i) {
    const int c = t * 4 + i;
    const float y = (v[i] - mu) * rstd * (float)g[c] + (float)be[c];
    if (fl) ((float*)out)[base + c] = y;
    else    ((bf16*)out)[base + c] = (bf16)y;
  }
}

// ---------------------------------------------------------------------------
extern "C" void kernel_launch(void* const* d_in, const int* in_sizes, int n_in,
                              void* d_out, int out_size, void* d_ws, size_t ws_size,
                              hipStream_t stream) {
  const void* x   = d_in[0];
  const void* Wq  = d_in[2];
  const void* bq  = d_in[3];
  const void* Wk  = d_in[4];
  const void* bk  = d_in[5];
  const void* Wv  = d_in[6];
  const void* bv  = d_in[7];
  const void* W1  = d_in[8];
  const void* b1  = d_in[9];
  const void* W2  = d_in[10];
  const void* b2  = d_in[11];
  const void* g1  = d_in[12];
  const void* be1 = d_in[13];
  const void* g2  = d_in[14];
  const void* be2 = d_in[15];

  const size_t MB = 1u << 20;
  char* w = (char*)d_ws;
  int*  flag = (int*)w;                       // 4 B
  bf16* sm   = (bf16*)(w + 65536);            // packed small vectors (~24 KB)
  bf16* bqkvc = sm + 0;        // 3072
  bf16* b1c   = sm + 3072;     // 4096
  bf16* b2c   = sm + 7168;     // 1024
  bf16* g1c   = sm + 8192;
  bf16* be1c  = sm + 9216;
  bf16* g2c   = sm + 10240;
  bf16* be2c  = sm + 11264;
  float* den0 = (float*)(w + 512 * 1024);   // [32][2048] f32 256 KB
  float* den1 = (float*)(w + 768 * 1024);   //            256 KB
  bf16* xc    = (bf16*)(w + 1 * MB);    // [4096][1024]    8 MB (dead after ln1)
  bf16* WqkvT = (bf16*)(w + 9 * MB);    // [3072][1024]    6 MB (dead after qkv)
  bf16* W1T   = (bf16*)(w + 15 * MB);   // [4096][1024]    8 MB (dead after ff1)
  bf16* W2T   = (bf16*)(w + 23 * MB);   // [1024][4096]    8 MB
  bf16* qkvb  = (bf16*)(w + 31 * MB);   // [4096][3072]   24 MB
  bf16* vT    = (bf16*)(w + 55 * MB);   // [32][64][2048]  8 MB
  bf16* op0   = (bf16*)(w + 63 * MB);   // [4096][1024]    8 MB (dead after ln1)
  bf16* op1   = (bf16*)(w + 71 * MB);   //                 8 MB (aliases h1b)
  bf16* h1b   = (bf16*)(w + 71 * MB);   //                 8 MB
  bf16* ff1   = (bf16*)(w + 31 * MB);   // [4096][4096]   32 MB (reuse qkvb+vT)
  float* facc = (float*)(w + 1 * MB);   // [4096][1024]f32 16 MB (reuse xc+WqkvT+W1T[:2])
  // peak 79 MB

  detect_dtype<<<1, 256, 0, stream>>>(x, flag);
  convert_x<<<4096, 256, 0, stream>>>(x, xc, flag);
  convert_small<<<16, 256, 0, stream>>>(bq, bk, bv, b1, b2, g1, be1, g2, be2,
                                        sm, flag);

  const dim3 tb(32, 8);
  transpose_w3<<<dim3(32, 32, 3), tb, 0, stream>>>(Wq, Wk, Wv, WqkvT, flag);
  transpose_w<<<dim3(128, 32), tb, 0, stream>>>(W1, W1T, 1024, 4096, flag);
  transpose_w<<<dim3(32, 128), tb, 0, stream>>>(W2, W2T, 4096, 1024, flag);

  // fused QKV: [4096][3072] = xc @ WqkvT^T + bqkv
  gemm_bt<<<dim3(24, 32), 256, 0, stream>>>(xc, WqkvT, bqkvc, qkvb,
                                            4096, 3072, 1024, 0);

  transpose_v<<<dim3(64, 2, 32), tb, 0, stream>>>(qkvb, vT);
  // split-KV attention: z = b*2 + kv_half; partials combined in ln1
  attn_kernel<<<dim3(16, 16, 4), 256, 0, stream>>>(qkvb, vT, op0, op1,
                                                   den0, den1);

  ln1_kernel<<<4096, 256, 0, stream>>>(xc, op0, op1, den0, den1,
                                       g1c, be1c, h1b);

  gemm_bt<<<dim3(32, 32), 256, 0, stream>>>(h1b, W1T, b1c, ff1,
                                            4096, 4096, 1024, 1);

  // ff2 split-K x4 -> f32 atomic accumulator (zeroed here; xc/WqkvT/W1T dead)
  (void)hipMemsetAsync(facc, 0, (size_t)4096 * 1024 * sizeof(float), stream);
  gemm_bt64_sk4<<<dim3(16, 32, 4), 256, 0, stream>>>(ff1, W2T, facc,
                                                     4096, 1024, 4096, 1024);

  ln2_kernel<<<4096, 256, 0, stream>>>(h1b, facc, b2c, g2c, be2c,
                                       d_out, flag);
}

// Round 13
// 382.299 us; speedup vs baseline: 1.1039x; 1.1039x over previous
//
#include <hip/hip_runtime.h>
#include <hip/hip_bf16.h>

// TransformerEncLayer on MI355X (gfx950). B=2, M=2048, d=1024, H=16, DK=64, FF=4096.
// Tokens = 4096. LN grids = 4096.
// R13: (1) REVERT ff2 atomics (R12: 98.7us, WRITE 64MB RMW ping-pong) back to
//      R10's split-K x2 bf16 dual partials (65.8us verified).
//      (2) gemm_bt BK 32->64: same 32KB LDS (four [128][32] chunks, m97 layout,
//      g2l16-compatible), half the barrier drains for the K=1024 GEMMs
//      (qkv, ff1), 32 MFMAs per barrier.
// Attention: split-KV x2 (R10) + exp2-domain Q prescale (R12). MFMA den (R9).

typedef __bf16 bf16;
typedef __attribute__((ext_vector_type(8))) __bf16 bf16x8;
typedef __attribute__((ext_vector_type(4))) __bf16 bf16x4;
typedef __attribute__((ext_vector_type(4))) float f32x4;

#define MFMA16(a, b, c) __builtin_amdgcn_mfma_f32_16x16x32_bf16(a, b, c, 0, 0, 0)

__device__ __forceinline__ void ld_g2l16(void* lds, const void* g) {
  __builtin_amdgcn_global_load_lds((const __attribute__((address_space(1))) void*)g,
                                   (__attribute__((address_space(3))) void*)lds,
                                   16, 0, 0);
}

// ---------------------------------------------------------------------------
// dtype detector (flag=1 -> fp32 inputs)
// ---------------------------------------------------------------------------
__global__ __launch_bounds__(256) void detect_dtype(const void* __restrict__ x,
                                                    int* __restrict__ flag) {
  const unsigned short* u = (const unsigned short*)x;
  int cnt = 0;
  for (int i = threadIdx.x; i < 4096; i += 256) {
    const int e = (u[i] >> 7) & 0xFF;
    if (e >= 140) ++cnt;
  }
  __shared__ int sh[256];
  sh[threadIdx.x] = cnt;
  __syncthreads();
  for (int s = 128; s > 0; s >>= 1) {
    if (threadIdx.x < s) sh[threadIdx.x] += sh[threadIdx.x + s];
    __syncthreads();
  }
  if (threadIdx.x == 0) *flag = (sh[0] > 100) ? 1 : 0;
}

__device__ __forceinline__ bf16 load_any(const void* p, size_t i, int fl) {
  return fl ? (bf16)((const float*)p)[i] : ((const bf16*)p)[i];
}

__global__ __launch_bounds__(256) void convert_x(const void* __restrict__ in,
                                                 bf16* __restrict__ o,
                                                 const int* __restrict__ flag) {
  const int fl = *flag;
  const size_t i0 = (size_t)(blockIdx.x * 256 + threadIdx.x) * 4;
#pragma unroll
  for (int i = 0; i < 4; ++i) o[i0 + i] = load_any(in, i0 + i, fl);
}

// small vectors -> packed bf16: bqkv[3072] | b1[4096] | b2 | g1 | be1 | g2 | be2
__global__ __launch_bounds__(256) void convert_small(
    const void* p0, const void* p1, const void* p2, const void* p3,
    const void* p4, const void* p5, const void* p6, const void* p7,
    const void* p8, bf16* __restrict__ dst, const int* __restrict__ flag) {
  const int fl = *flag;
  const int t = blockIdx.x * 256 + threadIdx.x;  // 0..4095
  const void* ps[9] = {p0, p1, p2, p3, p4, p5, p6, p7, p8};
  const int sz[9]  = {1024, 1024, 1024, 4096, 1024, 1024, 1024, 1024, 1024};
  const int off[9] = {0, 1024, 2048, 3072, 7168, 8192, 9216, 10240, 11264};
#pragma unroll
  for (int a = 0; a < 9; ++a)
    if (t < sz[a]) dst[off[a] + t] = load_any(ps[a], t, fl);
}

// ---------------------------------------------------------------------------
// flag-aware transpose: in[R][C] (bf16 or fp32) -> out[C][R] bf16.
// ---------------------------------------------------------------------------
__global__ __launch_bounds__(256) void transpose_w(const void* __restrict__ in,
                                                   bf16* __restrict__ out,
                                                   int R, int C,
                                                   const int* __restrict__ flag) {
  const int fl = *flag;
  __shared__ bf16 t[32][33];
  const int r0 = blockIdx.y * 32, c0 = blockIdx.x * 32;
  const int tx = threadIdx.x, ty = threadIdx.y;
#pragma unroll
  for (int i = ty; i < 32; i += 8)
    t[i][tx] = load_any(in, (size_t)(r0 + i) * C + c0 + tx, fl);
  __syncthreads();
#pragma unroll
  for (int i = ty; i < 32; i += 8)
    out[(size_t)(c0 + i) * R + r0 + tx] = t[tx][i];
}

// three 1024x1024 transposes in one launch (z selects Wq/Wk/Wv) -> WqkvT
__global__ __launch_bounds__(256) void transpose_w3(const void* __restrict__ q,
                                                    const void* __restrict__ k,
                                                    const void* __restrict__ v,
                                                    bf16* __restrict__ out,
                                                    const int* __restrict__ flag) {
  const int fl = *flag;
  const int z = blockIdx.z;
  const void* in = (z == 0) ? q : (z == 1) ? k : v;
  bf16* o = out + (size_t)z * 1024 * 1024;
  __shared__ bf16 t[32][33];
  const int r0 = blockIdx.y * 32, c0 = blockIdx.x * 32;
  const int tx = threadIdx.x, ty = threadIdx.y;
#pragma unroll
  for (int i = ty; i < 32; i += 8)
    t[i][tx] = load_any(in, (size_t)(r0 + i) * 1024 + c0 + tx, fl);
  __syncthreads();
#pragma unroll
  for (int i = ty; i < 32; i += 8)
    o[(size_t)(c0 + i) * 1024 + r0 + tx] = t[tx][i];
}

// ---------------------------------------------------------------------------
// V transpose per head from fused qkvb: qkvb[4096][3072] (v at col 2048+)
// -> vT[b*16+h][64][2048]
// ---------------------------------------------------------------------------
__global__ __launch_bounds__(256) void transpose_v(const bf16* __restrict__ qkvb,
                                                   bf16* __restrict__ vT) {
  __shared__ bf16 t[32][33];
  const int bh = blockIdx.z;
  const int b = bh >> 4, h = bh & 15;
  const int m0 = blockIdx.x * 32, d0 = blockIdx.y * 32;
  const int tx = threadIdx.x, ty = threadIdx.y;
#pragma unroll
  for (int i = ty; i < 32; i += 8)
    t[i][tx] = qkvb[(size_t)(b * 2048 + m0 + i) * 3072 + 2048 + h * 64 + d0 + tx];
  __syncthreads();
#pragma unroll
  for (int i = ty; i < 32; i += 8)
    vT[((size_t)bh * 64 + d0 + i) * 2048 + m0 + tx] = t[tx][i];
}

// ---------------------------------------------------------------------------
// bt-GEMM 128x128, BK=64: C = A @ BT^T + bias, optional ReLU.
// LDS: four [128][32] chunks (A k-lo/k-hi, B k-lo/k-hi) = 32 KB total,
// m97 layout per chunk (64B rows -> g2l16-compatible, verified conflict-free).
// Half the K-iterations (and barrier drains) of BK=32. K multiple of 64.
// ---------------------------------------------------------------------------
__global__ __launch_bounds__(256) void gemm_bt(const bf16* __restrict__ A,
                                               const bf16* __restrict__ BT,
                                               const bf16* __restrict__ bias,
                                               bf16* __restrict__ C,
                                               int M, int N, int K, int relu) {
  __shared__ bf16 sA[2][128 * 32];   // [k-chunk][row][32]
  __shared__ bf16 sB[2][128 * 32];
  const int tid = threadIdx.x;
  const int wave = tid >> 6, lane = tid & 63;
  const int wm = wave >> 1, wn = wave & 1;
  const int bm = blockIdx.y * 128, bn = blockIdx.x * 128;
  const int m16 = lane & 15, kg = lane >> 4;
  const int srow = lane >> 2;         // 0..15 within 16-row chunk
  const int scol = (lane & 3) * 8;    // 0,8,16,24

  f32x4 acc[4][4];
#pragma unroll
  for (int i = 0; i < 4; ++i)
#pragma unroll
    for (int j = 0; j < 4; ++j) acc[i][j] = (f32x4){0.f, 0.f, 0.f, 0.f};

  for (int k0 = 0; k0 < K; k0 += 64) {
    // stage: each wave stages rows [wave*32, wave*32+32) of all 4 chunks
#pragma unroll
    for (int i = 0; i < 2; ++i) {
      const int c = wave * 2 + i;          // 16-row chunk index 0..7
      const int row = c * 16 + srow;
#pragma unroll
      for (int h = 0; h < 2; ++h) {
        ld_g2l16(&sA[h][c * 512], A + (size_t)(bm + row) * K + k0 + h * 32 + scol);
        ld_g2l16(&sB[h][c * 512], BT + (size_t)(bn + row) * K + k0 + h * 32 + scol);
      }
    }
    __syncthreads();   // drains vmcnt -> staging visible

#pragma unroll
    for (int ks = 0; ks < 2; ++ks) {
      bf16x8 af[4], bfr[4];
#pragma unroll
      for (int t = 0; t < 4; ++t) {
        af[t]  = *(const bf16x8*)&sA[ks][(wm * 64 + t * 16 + m16) * 32 + kg * 8];
        bfr[t] = *(const bf16x8*)&sB[ks][(wn * 64 + t * 16 + m16) * 32 + kg * 8];
      }
#pragma unroll
      for (int mt = 0; mt < 4; ++mt)
#pragma unroll
        for (int nt = 0; nt < 4; ++nt)
          acc[mt][nt] = MFMA16(af[mt], bfr[nt], acc[mt][nt]);
    }
    __syncthreads();   // all reads done before next stage overwrites LDS
  }

  const int r0 = bm + wm * 64, c0 = bn + wn * 64;
#pragma unroll
  for (int nt = 0; nt < 4; ++nt) {
    const int col = c0 + nt * 16 + m16;
    const float bv = (float)bias[col];
#pragma unroll
    for (int mt = 0; mt < 4; ++mt) {
#pragma unroll
      for (int r = 0; r < 4; ++r) {
        const int row = r0 + mt * 16 + kg * 4 + r;
        float v = acc[mt][nt][r] + bv;
        if (relu) v = fmaxf(v, 0.f);
        C[(size_t)row * N + col] = (bf16)v;
      }
    }
  }
}

// ---------------------------------------------------------------------------
// Split-K bt-GEMM 128x64 tile: blockIdx.z selects K-half [z*Kp, z*Kp+Kp).
// Partial (no bias) written bf16 to C0 (z=0) or C1 (z=1). Kf = full K stride.
// (R8/R10-verified; R12's atomic variant regressed: 64MB RMW writes.)
// ---------------------------------------------------------------------------
__global__ __launch_bounds__(256) void gemm_bt64_sk(const bf16* __restrict__ A,
                                                    const bf16* __restrict__ BT,
                                                    bf16* __restrict__ C0,
                                                    bf16* __restrict__ C1,
                                                    int M, int N, int Kf, int Kp) {
  __shared__ bf16 sA[128 * 32];
  __shared__ bf16 sB[64 * 32];
  const int tid = threadIdx.x;
  const int wave = tid >> 6, lane = tid & 63;
  const int bm = blockIdx.y * 128, bn = blockIdx.x * 64;
  const int z = blockIdx.z;
  const int kbase = z * Kp;
  const int m16 = lane & 15, kg = lane >> 4;
  const int srow = lane >> 2;
  const int scol = (lane & 3) * 8;

  f32x4 acc[2][4];
#pragma unroll
  for (int i = 0; i < 2; ++i)
#pragma unroll
    for (int j = 0; j < 4; ++j) acc[i][j] = (f32x4){0.f, 0.f, 0.f, 0.f};

  for (int k0 = 0; k0 < Kp; k0 += 32) {
#pragma unroll
    for (int i = 0; i < 2; ++i) {
      const int c = wave * 2 + i;
      ld_g2l16(&sA[c * 512],
               A + (size_t)(bm + c * 16 + srow) * Kf + kbase + k0 + scol);
    }
    ld_g2l16(&sB[wave * 512],
             BT + (size_t)(bn + wave * 16 + srow) * Kf + kbase + k0 + scol);
    __syncthreads();

    bf16x8 af[2], bfr[4];
#pragma unroll
    for (int t = 0; t < 2; ++t)
      af[t] = *(const bf16x8*)&sA[(wave * 32 + t * 16 + m16) * 32 + kg * 8];
#pragma unroll
    for (int t = 0; t < 4; ++t)
      bfr[t] = *(const bf16x8*)&sB[(t * 16 + m16) * 32 + kg * 8];
#pragma unroll
    for (int mt = 0; mt < 2; ++mt)
#pragma unroll
      for (int nt = 0; nt < 4; ++nt)
        acc[mt][nt] = MFMA16(af[mt], bfr[nt], acc[mt][nt]);
    __syncthreads();
  }

  bf16* C = z ? C1 : C0;
  const int r0 = bm + wave * 32;
#pragma unroll
  for (int nt = 0; nt < 4; ++nt) {
    const int col = bn + nt * 16 + m16;
#pragma unroll
    for (int mt = 0; mt < 2; ++mt) {
#pragma unroll
      for (int r = 0; r < 4; ++r) {
        const int row = r0 + mt * 16 + kg * 4 + r;
        C[(size_t)row * N + col] = (bf16)acc[mt][nt][r];
      }
    }
  }
}

// ---------------------------------------------------------------------------
// Staged flash attention, split-KV x2. grid (16 qtiles, 16 heads, 4), z=b*2+kh.
// Q pre-scaled by log2(e)/1024 -> P = 2^S' via __builtin_amdgcn_exp2f.
// Unnormalized bf16 o partials + f32 den partials; combined in ln1.
// ---------------------------------------------------------------------------
__global__ __launch_bounds__(256) void attn_kernel(const bf16* __restrict__ qkvb,
                                                   const bf16* __restrict__ vT,
                                                   bf16* __restrict__ op0,
                                                   bf16* __restrict__ op1,
                                                   float* __restrict__ den0,
                                                   float* __restrict__ den1) {
  __shared__ bf16 sK[2][64 * 32];
  __shared__ bf16 sV[2][64 * 32];
  __shared__ bf16 pl[4][2][16 * 72];
  const int qt = blockIdx.x, h = blockIdx.y;
  const int b = blockIdx.z >> 1, kh = blockIdx.z & 1;
  const int tid = threadIdx.x, wv = tid >> 6, lane = tid & 63;
  const int m16 = lane & 15, kg = lane >> 4;
  const int srow = lane >> 2;
  const int scol = (lane & 3) * 8;

  // Q fragments pre-scaled by log2(e)/1024 -> S' = S*log2(e)/1024, P = 2^S'
  const float qs = 1.4426950408889634f / 1024.0f;
  bf16x8 fq0[2], fq1[2];
#pragma unroll
  for (int f = 0; f < 2; ++f) {
    const int q0 = qt * 128 + f * 64 + wv * 16;
    const bf16* qp = qkvb + (size_t)(b * 2048 + q0 + m16) * 3072 + h * 64;
    bf16x8 a = *(const bf16x8*)(qp + kg * 8);
    bf16x8 c = *(const bf16x8*)(qp + 32 + kg * 8);
#pragma unroll
    for (int i = 0; i < 8; ++i) {
      a[i] = (bf16)((float)a[i] * qs);
      c[i] = (bf16)((float)c[i] * qs);
    }
    fq0[f] = a;
    fq1[f] = c;
  }

  bf16x8 ones;
#pragma unroll
  for (int i = 0; i < 8; ++i) ones[i] = (bf16)1.0f;

  f32x4 o[2][4], oden[2];
#pragma unroll
  for (int f = 0; f < 2; ++f) {
#pragma unroll
    for (int c = 0; c < 4; ++c) o[f][c] = (f32x4){0.f, 0.f, 0.f, 0.f};
    oden[f] = (f32x4){0.f, 0.f, 0.f, 0.f};
  }

  const bf16* kbase = qkvb + (size_t)(b * 2048) * 3072 + 1024 + h * 64;
  const bf16* vbase = vT + (size_t)(b * 16 + h) * 64 * 2048;
  bf16* plw0 = &pl[wv][0][0];
  bf16* plw1 = &pl[wv][1][0];

  const int tstart = kh * 1024;
  for (int t0 = tstart; t0 < tstart + 1024; t0 += 64) {
    {
      const int row = wv * 16 + srow;
      ld_g2l16(&sK[0][wv * 512], kbase + (size_t)(t0 + row) * 3072 + scol);
      ld_g2l16(&sK[1][wv * 512], kbase + (size_t)(t0 + row) * 3072 + 32 + scol);
      ld_g2l16(&sV[0][wv * 512], vbase + (size_t)row * 2048 + t0 + scol);
      ld_g2l16(&sV[1][wv * 512], vbase + (size_t)row * 2048 + t0 + 32 + scol);
    }
    __syncthreads();

#pragma unroll
    for (int g = 0; g < 4; ++g) {
      const bf16x8 af0 = *(const bf16x8*)&sK[0][(g * 16 + m16) * 32 + kg * 8];
      const bf16x8 af1 = *(const bf16x8*)&sK[1][(g * 16 + m16) * 32 + kg * 8];
#pragma unroll
      for (int f = 0; f < 2; ++f) {
        f32x4 z = (f32x4){0.f, 0.f, 0.f, 0.f};
        z = MFMA16(af0, fq0[f], z);   // S'^T[t][q], exp2 domain
        z = MFMA16(af1, fq1[f], z);
        bf16x4 pv4;
#pragma unroll
        for (int r = 0; r < 4; ++r)
          pv4[r] = (bf16)__builtin_amdgcn_exp2f(z[r]);
        *(bf16x4*)((f ? plw1 : plw0) + m16 * 72 + g * 16 + kg * 4) = pv4;
      }
    }
    __asm__ __volatile__("s_waitcnt lgkmcnt(0)" ::: "memory");

#pragma unroll
    for (int tt = 0; tt < 2; ++tt) {
      const bf16x8 pa0 = *(const bf16x8*)(plw0 + m16 * 72 + tt * 32 + kg * 8);
      const bf16x8 pa1 = *(const bf16x8*)(plw1 + m16 * 72 + tt * 32 + kg * 8);
      oden[0] = MFMA16(pa0, ones, oden[0]);   // den[q=kg*4+r] in every col
      oden[1] = MFMA16(pa1, ones, oden[1]);
#pragma unroll
      for (int c = 0; c < 4; ++c) {
        const bf16x8 fv = *(const bf16x8*)&sV[tt][(c * 16 + m16) * 32 + kg * 8];
        o[0][c] = MFMA16(pa0, fv, o[0][c]);
        o[1][c] = MFMA16(pa1, fv, o[1][c]);
      }
    }
    __syncthreads();
  }

  bf16* op = kh ? op1 : op0;
  float* dptr = kh ? den1 : den0;
#pragma unroll
  for (int f = 0; f < 2; ++f)
#pragma unroll
    for (int r = 0; r < 4; ++r) {
      const int row = qt * 128 + f * 64 + wv * 16 + kg * 4 + r;  // q in [0,2048)
      if (m16 == 0) dptr[((b * 16 + h) << 11) + row] = oden[f][r];
      bf16* opp = op + (size_t)(b * 2048 + row) * 1024 + h * 64;
#pragma unroll
      for (int c = 0; c < 4; ++c) opp[c * 16 + m16] = (bf16)o[f][c][r];
    }
}

// ---------------------------------------------------------------------------
// LN1 + attention combine: attn = (op0+op1) / (den0+den1), then
// h1b = bf16( LN(x + attn)*g1 + be1 ). grid = 4096 rows.
// op1 aliases h1b: reads precede the barrier, writes follow; same-thread cover.
// ---------------------------------------------------------------------------
__global__ __launch_bounds__(256) void ln1_kernel(const bf16* __restrict__ x,
                                                  const bf16* __restrict__ op0,
                                                  const bf16* __restrict__ op1,
                                                  const float* __restrict__ den0,
                                                  const float* __restrict__ den1,
                                                  const bf16* __restrict__ g,
                                                  const bf16* __restrict__ be,
                                                  bf16* __restrict__ h1b) {
  const int row = blockIdx.x;           // b*2048 + q
  const int b = row >> 11, q = row & 2047;
  const size_t base = (size_t)row * 1024;
  const int t = threadIdx.x;
  const int h = t >> 4;                 // head of this thread's 4 columns
  const float rden = 1.0f / (den0[((b * 16 + h) << 11) + q] +
                             den1[((b * 16 + h) << 11) + q]);
  float v[4], s = 0.f, ss = 0.f;
#pragma unroll
  for (int i = 0; i < 4; ++i) {
    const int c = t * 4 + i;
    const float at = ((float)op0[base + c] + (float)op1[base + c]) * rden;
    const float xv = (float)x[base + c] + at;
    v[i] = xv; s += xv; ss += xv * xv;
  }
#pragma unroll
  for (int m = 1; m < 64; m <<= 1) { s += __shfl_xor(s, m); ss += __shfl_xor(ss, m); }
  __shared__ float rs[4], rss[4];
  const int wave = t >> 6, lane = t & 63;
  if (lane == 0) { rs[wave] = s; rss[wave] = ss; }
  __syncthreads();
  s = rs[0] + rs[1] + rs[2] + rs[3];
  ss = rss[0] + rss[1] + rss[2] + rss[3];
  const float mu = s * (1.f / 1024.f);
  const float var = fmaxf(ss * (1.f / 1024.f) - mu * mu, 0.f);
  const float rstd = rsqrtf(var + 1e-5f);
#pragma unroll
  for (int i = 0; i < 4; ++i) {
    const int c = t * 4 + i;
    h1b[base + c] = (bf16)((v[i] - mu) * rstd * (float)g[c] + (float)be[c]);
  }
}

// LN2: out = LN(h1b + p0 + p1 + b2)*g2 + be2 ; out dtype per flag. grid = 4096.
__global__ __launch_bounds__(256) void ln2_kernel(const bf16* __restrict__ h1b,
                                                  const bf16* __restrict__ p0,
                                                  const bf16* __restrict__ p1,
                                                  const bf16* __restrict__ b2,
                                                  const bf16* __restrict__ g,
                                                  const bf16* __restrict__ be,
                                                  void* __restrict__ out,
                                                  const int* __restrict__ flag) {
  const int fl = *flag;
  const int row = blockIdx.x;
  const size_t base = (size_t)row * 1024;
  const int t = threadIdx.x;
  float v[4], s = 0.f, ss = 0.f;
#pragma unroll
  for (int i = 0; i < 4; ++i) {
    const int c = t * 4 + i;
    const float xv = (float)h1b[base + c] + (float)p0[base + c] +
                     (float)p1[base + c] + (float)b2[c];
    v[i] = xv; s += xv; ss += xv * xv;
  }
#pragma unroll
  for (int m = 1; m < 64; m <<= 1) { s += __shfl_xor(s, m); ss += __shfl_xor(ss, m); }
  __shared__ float rs[4], rss[4];
  const int wave = t >> 6, lane = t & 63;
  if (lane == 0) { rs[wave] = s; rss[wave] = ss; }
  __syncthreads();
  s = rs[0] + rs[1] + rs[2] + rs[3];
  ss = rss[0] + rss[1] + rss[2] + rss[3];
  const float mu = s * (1.f / 1024.f);
  const float var = fmaxf(ss * (1.f / 1024.f) - mu * mu, 0.f);
  const float rstd = rsqrtf(var + 1e-5f);
#pragma unroll
  for (int i = 0; i < 4; ++i) {
    const int c = t * 4 + i;
    const float y = (v[i] - mu) * rstd * (float)g[c] + (float)be[c];
    if (fl) ((float*)out)[base + c] = y;
    else    ((bf16*)out)[base + c] = (bf16)y;
  }
}

// ---------------------------------------------------------------------------
extern "C" void kernel_launch(void* const* d_in, const int* in_sizes, int n_in,
                              void* d_out, int out_size, void* d_ws, size_t ws_size,
                              hipStream_t stream) {
  const void* x   = d_in[0];
  const void* Wq  = d_in[2];
  const void* bq  = d_in[3];
  const void* Wk  = d_in[4];
  const void* bk  = d_in[5];
  const void* Wv  = d_in[6];
  const void* bv  = d_in[7];
  const void* W1  = d_in[8];
  const void* b1  = d_in[9];
  const void* W2  = d_in[10];
  const void* b2  = d_in[11];
  const void* g1  = d_in[12];
  const void* be1 = d_in[13];
  const void* g2  = d_in[14];
  const void* be2 = d_in[15];

  const size_t MB = 1u << 20;
  char* w = (char*)d_ws;
  int*  flag = (int*)w;                       // 4 B
  bf16* sm   = (bf16*)(w + 65536);            // packed small vectors (~24 KB)
  bf16* bqkvc = sm + 0;        // 3072
  bf16* b1c   = sm + 3072;     // 4096
  bf16* b2c   = sm + 7168;     // 1024
  bf16* g1c   = sm + 8192;
  bf16* be1c  = sm + 9216;
  bf16* g2c   = sm + 10240;
  bf16* be2c  = sm + 11264;
  float* den0 = (float*)(w + 512 * 1024);   // [32][2048] f32 256 KB
  float* den1 = (float*)(w + 768 * 1024);   //            256 KB
  bf16* xc    = (bf16*)(w + 1 * MB);    // [4096][1024]    8 MB (dead after ln1)
  bf16* WqkvT = (bf16*)(w + 9 * MB);    // [3072][1024]    6 MB
  bf16* W1T   = (bf16*)(w + 15 * MB);   // [4096][1024]    8 MB
  bf16* W2T   = (bf16*)(w + 23 * MB);   // [1024][4096]    8 MB
  bf16* qkvb  = (bf16*)(w + 31 * MB);   // [4096][3072]   24 MB
  bf16* vT    = (bf16*)(w + 55 * MB);   // [32][64][2048]  8 MB
  bf16* op0   = (bf16*)(w + 63 * MB);   // [4096][1024]    8 MB (dead after ln1)
  bf16* op1   = (bf16*)(w + 71 * MB);   //                 8 MB (aliases h1b)
  bf16* h1b   = (bf16*)(w + 71 * MB);   //                 8 MB
  bf16* ff1   = (bf16*)(w + 31 * MB);   // [4096][4096]   32 MB (reuse qkvb+vT)
  bf16* ff2p0 = (bf16*)(w + 1 * MB);    // [4096][1024]    8 MB (reuse xc)
  bf16* ff2p1 = (bf16*)(w + 63 * MB);   //                 8 MB (reuse op0)
  // peak 79 MB

  detect_dtype<<<1, 256, 0, stream>>>(x, flag);
  convert_x<<<4096, 256, 0, stream>>>(x, xc, flag);
  convert_small<<<16, 256, 0, stream>>>(bq, bk, bv, b1, b2, g1, be1, g2, be2,
                                        sm, flag);

  const dim3 tb(32, 8);
  transpose_w3<<<dim3(32, 32, 3), tb, 0, stream>>>(Wq, Wk, Wv, WqkvT, flag);
  transpose_w<<<dim3(128, 32), tb, 0, stream>>>(W1, W1T, 1024, 4096, flag);
  transpose_w<<<dim3(32, 128), tb, 0, stream>>>(W2, W2T, 4096, 1024, flag);

  // fused QKV: [4096][3072] = xc @ WqkvT^T + bqkv   (BK=64 gemm)
  gemm_bt<<<dim3(24, 32), 256, 0, stream>>>(xc, WqkvT, bqkvc, qkvb,
                                            4096, 3072, 1024, 0);

  transpose_v<<<dim3(64, 2, 32), tb, 0, stream>>>(qkvb, vT);
  // split-KV attention: z = b*2 + kv_half; partials combined in ln1
  attn_kernel<<<dim3(16, 16, 4), 256, 0, stream>>>(qkvb, vT, op0, op1,
                                                   den0, den1);

  ln1_kernel<<<4096, 256, 0, stream>>>(xc, op0, op1, den0, den1,
                                       g1c, be1c, h1b);

  gemm_bt<<<dim3(32, 32), 256, 0, stream>>>(h1b, W1T, b1c, ff1,
                                            4096, 4096, 1024, 1);
  // ff2 split-K x2: bf16 partials (no bias) -> ff2p0 / ff2p1 (bias in ln2)
  gemm_bt64_sk<<<dim3(16, 32, 2), 256, 0, stream>>>(ff1, W2T, ff2p0, ff2p1,
                                                    4096, 1024, 4096, 2048);

  ln2_kernel<<<4096, 256, 0, stream>>>(h1b, ff2p0, ff2p1, b2c, g2c, be2c,
                                       d_out, flag);
}

// Round 14
// 377.469 us; speedup vs baseline: 1.1180x; 1.0128x over previous
//
#include <hip/hip_runtime.h>
#include <hip/hip_bf16.h>

// TransformerEncLayer on MI355X (gfx950). B=2, M=2048, d=1024, H=16, DK=64, FF=4096.
// Tokens = 4096. LN grids = 4096.
// R14: XCD-aware block swizzle on qkv/ff1/ff2 GEMMs. R13 evidence: ff2 FETCH
//  135 MB == 32r x 2z x 8XCD x 256KB A-slice -- every A-slice fetched into all
//  8 non-coherent L2s because column-tiles dispatch consecutively (round-robin
//  across XCDs). Remap linear block id so all column-tiles of a row share
//  L%8 -> one XCD per A-slice. Correctness is mapping-independent.
// Base: R13 (BK=64 gemm_bt, split-K x2 bf16 ff2, split-KV attn, exp2 softmax).

typedef __bf16 bf16;
typedef __attribute__((ext_vector_type(8))) __bf16 bf16x8;
typedef __attribute__((ext_vector_type(4))) __bf16 bf16x4;
typedef __attribute__((ext_vector_type(4))) float f32x4;

#define MFMA16(a, b, c) __builtin_amdgcn_mfma_f32_16x16x32_bf16(a, b, c, 0, 0, 0)

__device__ __forceinline__ void ld_g2l16(void* lds, const void* g) {
  __builtin_amdgcn_global_load_lds((const __attribute__((address_space(1))) void*)g,
                                   (__attribute__((address_space(3))) void*)lds,
                                   16, 0, 0);
}

// ---------------------------------------------------------------------------
// dtype detector (flag=1 -> fp32 inputs)
// ---------------------------------------------------------------------------
__global__ __launch_bounds__(256) void detect_dtype(const void* __restrict__ x,
                                                    int* __restrict__ flag) {
  const unsigned short* u = (const unsigned short*)x;
  int cnt = 0;
  for (int i = threadIdx.x; i < 4096; i += 256) {
    const int e = (u[i] >> 7) & 0xFF;
    if (e >= 140) ++cnt;
  }
  __shared__ int sh[256];
  sh[threadIdx.x] = cnt;
  __syncthreads();
  for (int s = 128; s > 0; s >>= 1) {
    if (threadIdx.x < s) sh[threadIdx.x] += sh[threadIdx.x + s];
    __syncthreads();
  }
  if (threadIdx.x == 0) *flag = (sh[0] > 100) ? 1 : 0;
}

__device__ __forceinline__ bf16 load_any(const void* p, size_t i, int fl) {
  return fl ? (bf16)((const float*)p)[i] : ((const bf16*)p)[i];
}

__global__ __launch_bounds__(256) void convert_x(const void* __restrict__ in,
                                                 bf16* __restrict__ o,
                                                 const int* __restrict__ flag) {
  const int fl = *flag;
  const size_t i0 = (size_t)(blockIdx.x * 256 + threadIdx.x) * 4;
#pragma unroll
  for (int i = 0; i < 4; ++i) o[i0 + i] = load_any(in, i0 + i, fl);
}

// small vectors -> packed bf16: bqkv[3072] | b1[4096] | b2 | g1 | be1 | g2 | be2
__global__ __launch_bounds__(256) void convert_small(
    const void* p0, const void* p1, const void* p2, const void* p3,
    const void* p4, const void* p5, const void* p6, const void* p7,
    const void* p8, bf16* __restrict__ dst, const int* __restrict__ flag) {
  const int fl = *flag;
  const int t = blockIdx.x * 256 + threadIdx.x;  // 0..4095
  const void* ps[9] = {p0, p1, p2, p3, p4, p5, p6, p7, p8};
  const int sz[9]  = {1024, 1024, 1024, 4096, 1024, 1024, 1024, 1024, 1024};
  const int off[9] = {0, 1024, 2048, 3072, 7168, 8192, 9216, 10240, 11264};
#pragma unroll
  for (int a = 0; a < 9; ++a)
    if (t < sz[a]) dst[off[a] + t] = load_any(ps[a], t, fl);
}

// ---------------------------------------------------------------------------
// flag-aware transpose: in[R][C] (bf16 or fp32) -> out[C][R] bf16.
// ---------------------------------------------------------------------------
__global__ __launch_bounds__(256) void transpose_w(const void* __restrict__ in,
                                                   bf16* __restrict__ out,
                                                   int R, int C,
                                                   const int* __restrict__ flag) {
  const int fl = *flag;
  __shared__ bf16 t[32][33];
  const int r0 = blockIdx.y * 32, c0 = blockIdx.x * 32;
  const int tx = threadIdx.x, ty = threadIdx.y;
#pragma unroll
  for (int i = ty; i < 32; i += 8)
    t[i][tx] = load_any(in, (size_t)(r0 + i) * C + c0 + tx, fl);
  __syncthreads();
#pragma unroll
  for (int i = ty; i < 32; i += 8)
    out[(size_t)(c0 + i) * R + r0 + tx] = t[tx][i];
}

// three 1024x1024 transposes in one launch (z selects Wq/Wk/Wv) -> WqkvT
__global__ __launch_bounds__(256) void transpose_w3(const void* __restrict__ q,
                                                    const void* __restrict__ k,
                                                    const void* __restrict__ v,
                                                    bf16* __restrict__ out,
                                                    const int* __restrict__ flag) {
  const int fl = *flag;
  const int z = blockIdx.z;
  const void* in = (z == 0) ? q : (z == 1) ? k : v;
  bf16* o = out + (size_t)z * 1024 * 1024;
  __shared__ bf16 t[32][33];
  const int r0 = blockIdx.y * 32, c0 = blockIdx.x * 32;
  const int tx = threadIdx.x, ty = threadIdx.y;
#pragma unroll
  for (int i = ty; i < 32; i += 8)
    t[i][tx] = load_any(in, (size_t)(r0 + i) * 1024 + c0 + tx, fl);
  __syncthreads();
#pragma unroll
  for (int i = ty; i < 32; i += 8)
    o[(size_t)(c0 + i) * 1024 + r0 + tx] = t[tx][i];
}

// ---------------------------------------------------------------------------
// V transpose per head from fused qkvb: qkvb[4096][3072] (v at col 2048+)
// -> vT[b*16+h][64][2048]
// ---------------------------------------------------------------------------
__global__ __launch_bounds__(256) void transpose_v(const bf16* __restrict__ qkvb,
                                                   bf16* __restrict__ vT) {
  __shared__ bf16 t[32][33];
  const int bh = blockIdx.z;
  const int b = bh >> 4, h = bh & 15;
  const int m0 = blockIdx.x * 32, d0 = blockIdx.y * 32;
  const int tx = threadIdx.x, ty = threadIdx.y;
#pragma unroll
  for (int i = ty; i < 32; i += 8)
    t[i][tx] = qkvb[(size_t)(b * 2048 + m0 + i) * 3072 + 2048 + h * 64 + d0 + tx];
  __syncthreads();
#pragma unroll
  for (int i = ty; i < 32; i += 8)
    vT[((size_t)bh * 64 + d0 + i) * 2048 + m0 + tx] = t[tx][i];
}

// ---------------------------------------------------------------------------
// bt-GEMM 128x128, BK=64, XCD-swizzled 1D grid (gx*32 blocks).
// Decode: L=(r%8) + 8*(c + gx*(r/8)) -> all column-tiles of row r share L%8
// (same XCD under round-robin assignment) -> A-slice fetched into one L2.
// ---------------------------------------------------------------------------
__global__ __launch_bounds__(256) void gemm_bt(const bf16* __restrict__ A,
                                               const bf16* __restrict__ BT,
                                               const bf16* __restrict__ bias,
                                               bf16* __restrict__ C,
                                               int M, int N, int K, int relu) {
  __shared__ bf16 sA[2][128 * 32];   // [k-chunk][row][32]
  __shared__ bf16 sB[2][128 * 32];
  const int tid = threadIdx.x;
  const int wave = tid >> 6, lane = tid & 63;
  const int wm = wave >> 1, wn = wave & 1;
  // XCD-aware decode of 1D block id
  const int gx = N >> 7;               // column tiles
  const int L = blockIdx.x;
  const int x8 = L & 7;
  const int t1 = L >> 3;
  const int cb = t1 % gx;
  const int rb = (t1 / gx) * 8 + x8;   // row tile, rb%8 == L%8
  const int bm = rb * 128, bn = cb * 128;
  const int m16 = lane & 15, kg = lane >> 4;
  const int srow = lane >> 2;
  const int scol = (lane & 3) * 8;

  f32x4 acc[4][4];
#pragma unroll
  for (int i = 0; i < 4; ++i)
#pragma unroll
    for (int j = 0; j < 4; ++j) acc[i][j] = (f32x4){0.f, 0.f, 0.f, 0.f};

  for (int k0 = 0; k0 < K; k0 += 64) {
#pragma unroll
    for (int i = 0; i < 2; ++i) {
      const int c = wave * 2 + i;          // 16-row chunk index 0..7
      const int row = c * 16 + srow;
#pragma unroll
      for (int h = 0; h < 2; ++h) {
        ld_g2l16(&sA[h][c * 512], A + (size_t)(bm + row) * K + k0 + h * 32 + scol);
        ld_g2l16(&sB[h][c * 512], BT + (size_t)(bn + row) * K + k0 + h * 32 + scol);
      }
    }
    __syncthreads();

#pragma unroll
    for (int ks = 0; ks < 2; ++ks) {
      bf16x8 af[4], bfr[4];
#pragma unroll
      for (int t = 0; t < 4; ++t) {
        af[t]  = *(const bf16x8*)&sA[ks][(wm * 64 + t * 16 + m16) * 32 + kg * 8];
        bfr[t] = *(const bf16x8*)&sB[ks][(wn * 64 + t * 16 + m16) * 32 + kg * 8];
      }
#pragma unroll
      for (int mt = 0; mt < 4; ++mt)
#pragma unroll
        for (int nt = 0; nt < 4; ++nt)
          acc[mt][nt] = MFMA16(af[mt], bfr[nt], acc[mt][nt]);
    }
    __syncthreads();
  }

  const int r0 = bm + wm * 64, c0 = bn + wn * 64;
#pragma unroll
  for (int nt = 0; nt < 4; ++nt) {
    const int col = c0 + nt * 16 + m16;
    const float bv = (float)bias[col];
#pragma unroll
    for (int mt = 0; mt < 4; ++mt) {
#pragma unroll
      for (int r = 0; r < 4; ++r) {
        const int row = r0 + mt * 16 + kg * 4 + r;
        float v = acc[mt][nt][r] + bv;
        if (relu) v = fmaxf(v, 0.f);
        C[(size_t)row * N + col] = (bf16)v;
      }
    }
  }
}

// ---------------------------------------------------------------------------
// Split-K bt-GEMM 128x64, XCD-swizzled 1D grid (1024 blocks).
// L = (r%8) + 8*(c + 16*(z + 2*(r/8))); c in [0,16), z in [0,2), r in [0,32).
// bf16 partials (no bias) to C0/C1 by z.
// ---------------------------------------------------------------------------
__global__ __launch_bounds__(256) void gemm_bt64_sk(const bf16* __restrict__ A,
                                                    const bf16* __restrict__ BT,
                                                    bf16* __restrict__ C0,
                                                    bf16* __restrict__ C1,
                                                    int M, int N, int Kf, int Kp) {
  __shared__ bf16 sA[128 * 32];
  __shared__ bf16 sB[64 * 32];
  const int tid = threadIdx.x;
  const int wave = tid >> 6, lane = tid & 63;
  const int L = blockIdx.x;
  const int x8 = L & 7;
  const int t1 = L >> 3;
  const int cb = t1 & 15;
  const int u = t1 >> 4;
  const int z = u & 1;
  const int rb = (u >> 1) * 8 + x8;
  const int bm = rb * 128, bn = cb * 64;
  const int kbase = z * Kp;
  const int m16 = lane & 15, kg = lane >> 4;
  const int srow = lane >> 2;
  const int scol = (lane & 3) * 8;

  f32x4 acc[2][4];
#pragma unroll
  for (int i = 0; i < 2; ++i)
#pragma unroll
    for (int j = 0; j < 4; ++j) acc[i][j] = (f32x4){0.f, 0.f, 0.f, 0.f};

  for (int k0 = 0; k0 < Kp; k0 += 32) {
#pragma unroll
    for (int i = 0; i < 2; ++i) {
      const int c = wave * 2 + i;
      ld_g2l16(&sA[c * 512],
               A + (size_t)(bm + c * 16 + srow) * Kf + kbase + k0 + scol);
    }
    ld_g2l16(&sB[wave * 512],
             BT + (size_t)(bn + wave * 16 + srow) * Kf + kbase + k0 + scol);
    __syncthreads();

    bf16x8 af[2], bfr[4];
#pragma unroll
    for (int t = 0; t < 2; ++t)
      af[t] = *(const bf16x8*)&sA[(wave * 32 + t * 16 + m16) * 32 + kg * 8];
#pragma unroll
    for (int t = 0; t < 4; ++t)
      bfr[t] = *(const bf16x8*)&sB[(t * 16 + m16) * 32 + kg * 8];
#pragma unroll
    for (int mt = 0; mt < 2; ++mt)
#pragma unroll
      for (int nt = 0; nt < 4; ++nt)
        acc[mt][nt] = MFMA16(af[mt], bfr[nt], acc[mt][nt]);
    __syncthreads();
  }

  bf16* C = z ? C1 : C0;
  const int r0 = bm + wave * 32;
#pragma unroll
  for (int nt = 0; nt < 4; ++nt) {
    const int col = bn + nt * 16 + m16;
#pragma unroll
    for (int mt = 0; mt < 2; ++mt) {
#pragma unroll
      for (int r = 0; r < 4; ++r) {
        const int row = r0 + mt * 16 + kg * 4 + r;
        C[(size_t)row * N + col] = (bf16)acc[mt][nt][r];
      }
    }
  }
}

// ---------------------------------------------------------------------------
// Staged flash attention, split-KV x2. grid (16 qtiles, 16 heads, 4), z=b*2+kh.
// Q pre-scaled by log2(e)/1024 -> P = 2^S' via __builtin_amdgcn_exp2f.
// Unnormalized bf16 o partials + f32 den partials; combined in ln1.
// ---------------------------------------------------------------------------
__global__ __launch_bounds__(256) void attn_kernel(const bf16* __restrict__ qkvb,
                                                   const bf16* __restrict__ vT,
                                                   bf16* __restrict__ op0,
                                                   bf16* __restrict__ op1,
                                                   float* __restrict__ den0,
                                                   float* __restrict__ den1) {
  __shared__ bf16 sK[2][64 * 32];
  __shared__ bf16 sV[2][64 * 32];
  __shared__ bf16 pl[4][2][16 * 72];
  const int qt = blockIdx.x, h = blockIdx.y;
  const int b = blockIdx.z >> 1, kh = blockIdx.z & 1;
  const int tid = threadIdx.x, wv = tid >> 6, lane = tid & 63;
  const int m16 = lane & 15, kg = lane >> 4;
  const int srow = lane >> 2;
  const int scol = (lane & 3) * 8;

  const float qs = 1.4426950408889634f / 1024.0f;
  bf16x8 fq0[2], fq1[2];
#pragma unroll
  for (int f = 0; f < 2; ++f) {
    const int q0 = qt * 128 + f * 64 + wv * 16;
    const bf16* qp = qkvb + (size_t)(b * 2048 + q0 + m16) * 3072 + h * 64;
    bf16x8 a = *(const bf16x8*)(qp + kg * 8);
    bf16x8 c = *(const bf16x8*)(qp + 32 + kg * 8);
#pragma unroll
    for (int i = 0; i < 8; ++i) {
      a[i] = (bf16)((float)a[i] * qs);
      c[i] = (bf16)((float)c[i] * qs);
    }
    fq0[f] = a;
    fq1[f] = c;
  }

  bf16x8 ones;
#pragma unroll
  for (int i = 0; i < 8; ++i) ones[i] = (bf16)1.0f;

  f32x4 o[2][4], oden[2];
#pragma unroll
  for (int f = 0; f < 2; ++f) {
#pragma unroll
    for (int c = 0; c < 4; ++c) o[f][c] = (f32x4){0.f, 0.f, 0.f, 0.f};
    oden[f] = (f32x4){0.f, 0.f, 0.f, 0.f};
  }

  const bf16* kbase = qkvb + (size_t)(b * 2048) * 3072 + 1024 + h * 64;
  const bf16* vbase = vT + (size_t)(b * 16 + h) * 64 * 2048;
  bf16* plw0 = &pl[wv][0][0];
  bf16* plw1 = &pl[wv][1][0];

  const int tstart = kh * 1024;
  for (int t0 = tstart; t0 < tstart + 1024; t0 += 64) {
    {
      const int row = wv * 16 + srow;
      ld_g2l16(&sK[0][wv * 512], kbase + (size_t)(t0 + row) * 3072 + scol);
      ld_g2l16(&sK[1][wv * 512], kbase + (size_t)(t0 + row) * 3072 + 32 + scol);
      ld_g2l16(&sV[0][wv * 512], vbase + (size_t)row * 2048 + t0 + scol);
      ld_g2l16(&sV[1][wv * 512], vbase + (size_t)row * 2048 + t0 + 32 + scol);
    }
    __syncthreads();

#pragma unroll
    for (int g = 0; g < 4; ++g) {
      const bf16x8 af0 = *(const bf16x8*)&sK[0][(g * 16 + m16) * 32 + kg * 8];
      const bf16x8 af1 = *(const bf16x8*)&sK[1][(g * 16 + m16) * 32 + kg * 8];
#pragma unroll
      for (int f = 0; f < 2; ++f) {
        f32x4 z = (f32x4){0.f, 0.f, 0.f, 0.f};
        z = MFMA16(af0, fq0[f], z);   // S'^T[t][q], exp2 domain
        z = MFMA16(af1, fq1[f], z);
        bf16x4 pv4;
#pragma unroll
        for (int r = 0; r < 4; ++r)
          pv4[r] = (bf16)__builtin_amdgcn_exp2f(z[r]);
        *(bf16x4*)((f ? plw1 : plw0) + m16 * 72 + g * 16 + kg * 4) = pv4;
      }
    }
    __asm__ __volatile__("s_waitcnt lgkmcnt(0)" ::: "memory");

#pragma unroll
    for (int tt = 0; tt < 2; ++tt) {
      const bf16x8 pa0 = *(const bf16x8*)(plw0 + m16 * 72 + tt * 32 + kg * 8);
      const bf16x8 pa1 = *(const bf16x8*)(plw1 + m16 * 72 + tt * 32 + kg * 8);
      oden[0] = MFMA16(pa0, ones, oden[0]);
      oden[1] = MFMA16(pa1, ones, oden[1]);
#pragma unroll
      for (int c = 0; c < 4; ++c) {
        const bf16x8 fv = *(const bf16x8*)&sV[tt][(c * 16 + m16) * 32 + kg * 8];
        o[0][c] = MFMA16(pa0, fv, o[0][c]);
        o[1][c] = MFMA16(pa1, fv, o[1][c]);
      }
    }
    __syncthreads();
  }

  bf16* op = kh ? op1 : op0;
  float* dptr = kh ? den1 : den0;
#pragma unroll
  for (int f = 0; f < 2; ++f)
#pragma unroll
    for (int r = 0; r < 4; ++r) {
      const int row = qt * 128 + f * 64 + wv * 16 + kg * 4 + r;
      if (m16 == 0) dptr[((b * 16 + h) << 11) + row] = oden[f][r];
      bf16* opp = op + (size_t)(b * 2048 + row) * 1024 + h * 64;
#pragma unroll
      for (int c = 0; c < 4; ++c) opp[c * 16 + m16] = (bf16)o[f][c][r];
    }
}

// ---------------------------------------------------------------------------
// LN1 + attention combine: attn = (op0+op1) / (den0+den1), then
// h1b = bf16( LN(x + attn)*g1 + be1 ). grid = 4096 rows.
// op1 aliases h1b: reads precede the barrier, writes follow; same-thread cover.
// ---------------------------------------------------------------------------
__global__ __launch_bounds__(256) void ln1_kernel(const bf16* __restrict__ x,
                                                  const bf16* __restrict__ op0,
                                                  const bf16* __restrict__ op1,
                                                  const float* __restrict__ den0,
                                                  const float* __restrict__ den1,
                                                  const bf16* __restrict__ g,
                                                  const bf16* __restrict__ be,
                                                  bf16* __restrict__ h1b) {
  const int row = blockIdx.x;           // b*2048 + q
  const int b = row >> 11, q = row & 2047;
  const size_t base = (size_t)row * 1024;
  const int t = threadIdx.x;
  const int h = t >> 4;                 // head of this thread's 4 columns
  const float rden = 1.0f / (den0[((b * 16 + h) << 11) + q] +
                             den1[((b * 16 + h) << 11) + q]);
  float v[4], s = 0.f, ss = 0.f;
#pragma unroll
  for (int i = 0; i < 4; ++i) {
    const int c = t * 4 + i;
    const float at = ((float)op0[base + c] + (float)op1[base + c]) * rden;
    const float xv = (float)x[base + c] + at;
    v[i] = xv; s += xv; ss += xv * xv;
  }
#pragma unroll
  for (int m = 1; m < 64; m <<= 1) { s += __shfl_xor(s, m); ss += __shfl_xor(ss, m); }
  __shared__ float rs[4], rss[4];
  const int wave = t >> 6, lane = t & 63;
  if (lane == 0) { rs[wave] = s; rss[wave] = ss; }
  __syncthreads();
  s = rs[0] + rs[1] + rs[2] + rs[3];
  ss = rss[0] + rss[1] + rss[2] + rss[3];
  const float mu = s * (1.f / 1024.f);
  const float var = fmaxf(ss * (1.f / 1024.f) - mu * mu, 0.f);
  const float rstd = rsqrtf(var + 1e-5f);
#pragma unroll
  for (int i = 0; i < 4; ++i) {
    const int c = t * 4 + i;
    h1b[base + c] = (bf16)((v[i] - mu) * rstd * (float)g[c] + (float)be[c]);
  }
}

// LN2: out = LN(h1b + p0 + p1 + b2)*g2 + be2 ; out dtype per flag. grid = 4096.
__global__ __launch_bounds__(256) void ln2_kernel(const bf16* __restrict__ h1b,
                                                  const bf16* __restrict__ p0,
                                                  const bf16* __restrict__ p1,
                                                  const bf16* __restrict__ b2,
                                                  const bf16* __restrict__ g,
                                                  const bf16* __restrict__ be,
                                                  void* __restrict__ out,
                                                  const int* __restrict__ flag) {
  const int fl = *flag;
  const int row = blockIdx.x;
  const size_t base = (size_t)row * 1024;
  const int t = threadIdx.x;
  float v[4], s = 0.f, ss = 0.f;
#pragma unroll
  for (int i = 0; i < 4; ++i) {
    const int c = t * 4 + i;
    const float xv = (float)h1b[base + c] + (float)p0[base + c] +
                     (float)p1[base + c] + (float)b2[c];
    v[i] = xv; s += xv; ss += xv * xv;
  }
#pragma unroll
  for (int m = 1; m < 64; m <<= 1) { s += __shfl_xor(s, m); ss += __shfl_xor(ss, m); }
  __shared__ float rs[4], rss[4];
  const int wave = t >> 6, lane = t & 63;
  if (lane == 0) { rs[wave] = s; rss[wave] = ss; }
  __syncthreads();
  s = rs[0] + rs[1] + rs[2] + rs[3];
  ss = rss[0] + rss[1] + rss[2] + rss[3];
  const float mu = s * (1.f / 1024.f);
  const float var = fmaxf(ss * (1.f / 1024.f) - mu * mu, 0.f);
  const float rstd = rsqrtf(var + 1e-5f);
#pragma unroll
  for (int i = 0; i < 4; ++i) {
    const int c = t * 4 + i;
    const float y = (v[i] - mu) * rstd * (float)g[c] + (float)be[c];
    if (fl) ((float*)out)[base + c] = y;
    else    ((bf16*)out)[base + c] = (bf16)y;
  }
}

// ---------------------------------------------------------------------------
extern "C" void kernel_launch(void* const* d_in, const int* in_sizes, int n_in,
                              void* d_out, int out_size, void* d_ws, size_t ws_size,
                              hipStream_t stream) {
  const void* x   = d_in[0];
  const void* Wq  = d_in[2];
  const void* bq  = d_in[3];
  const void* Wk  = d_in[4];
  const void* bk  = d_in[5];
  const void* Wv  = d_in[6];
  const void* bv  = d_in[7];
  const void* W1  = d_in[8];
  const void* b1  = d_in[9];
  const void* W2  = d_in[10];
  const void* b2  = d_in[11];
  const void* g1  = d_in[12];
  const void* be1 = d_in[13];
  const void* g2  = d_in[14];
  const void* be2 = d_in[15];

  const size_t MB = 1u << 20;
  char* w = (char*)d_ws;
  int*  flag = (int*)w;                       // 4 B
  bf16* sm   = (bf16*)(w + 65536);            // packed small vectors (~24 KB)
  bf16* bqkvc = sm + 0;        // 3072
  bf16* b1c   = sm + 3072;     // 4096
  bf16* b2c   = sm + 7168;     // 1024
  bf16* g1c   = sm + 8192;
  bf16* be1c  = sm + 9216;
  bf16* g2c   = sm + 10240;
  bf16* be2c  = sm + 11264;
  float* den0 = (float*)(w + 512 * 1024);   // [32][2048] f32 256 KB
  float* den1 = (float*)(w + 768 * 1024);   //            256 KB
  bf16* xc    = (bf16*)(w + 1 * MB);    // [4096][1024]    8 MB (dead after ln1)
  bf16* WqkvT = (bf16*)(w + 9 * MB);    // [3072][1024]    6 MB
  bf16* W1T   = (bf16*)(w + 15 * MB);   // [4096][1024]    8 MB
  bf16* W2T   = (bf16*)(w + 23 * MB);   // [1024][4096]    8 MB
  bf16* qkvb  = (bf16*)(w + 31 * MB);   // [4096][3072]   24 MB
  bf16* vT    = (bf16*)(w + 55 * MB);   // [32][64][2048]  8 MB
  bf16* op0   = (bf16*)(w + 63 * MB);   // [4096][1024]    8 MB (dead after ln1)
  bf16* op1   = (bf16*)(w + 71 * MB);   //                 8 MB (aliases h1b)
  bf16* h1b   = (bf16*)(w + 71 * MB);   //                 8 MB
  bf16* ff1   = (bf16*)(w + 31 * MB);   // [4096][4096]   32 MB (reuse qkvb+vT)
  bf16* ff2p0 = (bf16*)(w + 1 * MB);    // [4096][1024]    8 MB (reuse xc)
  bf16* ff2p1 = (bf16*)(w + 63 * MB);   //                 8 MB (reuse op0)
  // peak 79 MB

  detect_dtype<<<1, 256, 0, stream>>>(x, flag);
  convert_x<<<4096, 256, 0, stream>>>(x, xc, flag);
  convert_small<<<16, 256, 0, stream>>>(bq, bk, bv, b1, b2, g1, be1, g2, be2,
                                        sm, flag);

  const dim3 tb(32, 8);
  transpose_w3<<<dim3(32, 32, 3), tb, 0, stream>>>(Wq, Wk, Wv, WqkvT, flag);
  transpose_w<<<dim3(128, 32), tb, 0, stream>>>(W1, W1T, 1024, 4096, flag);
  transpose_w<<<dim3(32, 128), tb, 0, stream>>>(W2, W2T, 4096, 1024, flag);

  // fused QKV: [4096][3072] = xc @ WqkvT^T + bqkv  (BK=64, XCD swizzle, 1D grid)
  gemm_bt<<<24 * 32, 256, 0, stream>>>(xc, WqkvT, bqkvc, qkvb,
                                       4096, 3072, 1024, 0);

  transpose_v<<<dim3(64, 2, 32), tb, 0, stream>>>(qkvb, vT);
  // split-KV attention: z = b*2 + kv_half; partials combined in ln1
  attn_kernel<<<dim3(16, 16, 4), 256, 0, stream>>>(qkvb, vT, op0, op1,
                                                   den0, den1);

  ln1_kernel<<<4096, 256, 0, stream>>>(xc, op0, op1, den0, den1,
                                       g1c, be1c, h1b);

  gemm_bt<<<32 * 32, 256, 0, stream>>>(h1b, W1T, b1c, ff1,
                                       4096, 4096, 1024, 1);
  // ff2 split-K x2: bf16 partials, XCD-swizzled 1D grid (1024 blocks)
  gemm_bt64_sk<<<1024, 256, 0, stream>>>(ff1, W2T, ff2p0, ff2p1,
                                         4096, 1024, 4096, 2048);

  ln2_kernel<<<4096, 256, 0, stream>>>(h1b, ff2p0, ff2p1, b2c, g2c, be2c,
                                       d_out, flag);
}